// Round 1
// baseline (604.121 us; speedup 1.0000x reference)
//
#include <hip/hip_runtime.h>

#define B_ 128
#define S_ 48
#define P_ 60
#define I_ 512
#define H_ 512
#define G3 1536   // 3*H
#define NF_ 4
#define O_ 2

typedef __bf16 bf16x8 __attribute__((ext_vector_type(8)));
typedef float f32x4 __attribute__((ext_vector_type(4)));
typedef unsigned long long u64;

// ---------------- K1: fused alpha + emb (single pass over 755MB inputs) ----------------
__global__ __launch_bounds__(960) void k_alpha_emb(
    const float* __restrict__ x, const float* __restrict__ cw,
    const float* __restrict__ cb, float* __restrict__ alpha_out,
    __bf16* __restrict__ emb_bf)
{
  int bs   = blockIdx.x;
  int tid  = threadIdx.x;
  int wave = tid >> 6, lane = tid & 63;
  const float* xb = x + (size_t)bs * (P_ * I_);

  float w[8];
  {
    const float4* c4 = (const float4*)(cw + lane * 8);
    float4 a = c4[0], b = c4[1];
    w[0]=a.x; w[1]=a.y; w[2]=a.z; w[3]=a.w; w[4]=b.x; w[5]=b.y; w[6]=b.z; w[7]=b.w;
  }
  float cb0 = cb[0];
  float acc[8] = {0,0,0,0,0,0,0,0};
  __shared__ float part[15][512];

  for (int p = wave; p < P_; p += 15) {
    const float4* xr = (const float4*)(xb + (size_t)p * I_ + lane * 8);
    float4 a = xr[0], b = xr[1];
    float xv[8] = {a.x,a.y,a.z,a.w,b.x,b.y,b.z,b.w};
    float d = 0.f;
    #pragma unroll
    for (int j = 0; j < 8; j++) d += xv[j] * w[j];
    #pragma unroll
    for (int off = 32; off >= 1; off >>= 1) d += __shfl_xor(d, off);
    float al = fminf(fmaxf(d + cb0, 0.f), 1.f);
    if (lane == 0) alpha_out[(size_t)bs * P_ + p] = al;
    #pragma unroll
    for (int j = 0; j < 8; j++) acc[j] += al * xv[j];
  }
  #pragma unroll
  for (int j = 0; j < 8; j++) part[wave][lane * 8 + j] = acc[j];
  __syncthreads();
  if (tid < 512) {
    float s = 0.f;
    #pragma unroll
    for (int wv = 0; wv < 15; wv++) s += part[wv][tid];
    emb_bf[(size_t)bs * I_ + tid] = (__bf16)s;   // layout [b][s][k]
  }
}

// ---------------- K3: ALL 48 GRU steps, persistent, x-projection FUSED ----------------
// 128 blocks x 256 threads (cooperative launch for co-residency only).
// Block = (dir, batch-half of 64, j-chunk of 16); sync group = 32 blocks of one
// (dir, batch-half). R15: PER-STEP h buffers (written once, immutable after
// their flag) — run-ahead allowed, no buffer reuse.
// R16 (this round): critical-chain reschedule, protocol semantics preserved:
//   (a) xp MFMAs (emb x Wih — flag-independent) hoisted BEFORE the flag poll,
//       so the wait-for-producers overlaps ~1us of useful work and the
//       post-poll chain is only h-load -> 48 h-MFMAs -> nonlin -> release.
//   (b) per-WAVE flags: each wave acks its own 512B h-store with inline
//       s_waitcnt vmcnt(0) (memory clobber) then lane0 sets its flag slot.
//       Removes the end-of-step __syncthreads (write-once buffers => the
//       removed barrier guarded no WAR hazard) + thread0 serialization.
//       Release invariant unchanged: sc1 stores -> vmcnt(0) ack -> flag.
//   (c) hs (fp32, consumed by k_attn after dispatch boundary) stored AFTER
//       the release; its ack folds into the NEXT step's vmcnt(0), off-chain.
// Flags: [step][4 grp][32 blk][4 wave] x 16B slots (one 64B line per block;
// same 32 polled lines per consumer as R15). 1 barrier/step (was 2).
__global__ __launch_bounds__(256) void k_gru_all(
    const float* __restrict__ whh_f, const float* __restrict__ whh_b,
    const float* __restrict__ wih_f, const float* __restrict__ wih_b,
    const float* __restrict__ bhh_f, const float* __restrict__ bhh_b,
    const float* __restrict__ bih_f, const float* __restrict__ bih_b,
    const __bf16* __restrict__ emb,      // [B][S][I] bf16
    u64* __restrict__ hbf,               // [S+1][2 dir][B][H/4] bf16x4-as-u64
    float* __restrict__ hs,              // [B][S][2H] fp32
    unsigned* __restrict__ bar)          // [S][4 grp][32 blk][4 wave] x 4-u32 stride
{
  int bid = blockIdx.x;
  int dir = bid >> 6;                    // 64 blocks per dir
  int j0  = (bid & 31) * 16;             // j-chunk of 16
  int m0  = ((bid >> 5) & 1) * 64;       // batch-half of 64
  int myi = bid & 31;                    // index within sync group
  int grp = bid >> 5;                    // group = (dir, batch-half), 0..3
  const float* Whh_d = dir ? whh_b : whh_f;    // fp32 [3H][I]
  const float* Wih_d = dir ? wih_b : wih_f;

  // weight slices in LDS: rows = 3 gates x 16 j, 512 k; 16B-granule XOR swizzle.
  __shared__ __bf16 Ahh[48 * 512];
  __shared__ __bf16 Aih[48 * 512];
  for (int it = threadIdx.x; it < 48 * 64; it += 256) {
    int r = it >> 6, c8 = it & 63;
    int grow = (r >> 4) * H_ + j0 + (r & 15);
    int dst = r * 512 + ((c8 ^ (r & 7)) * 8);
    const float* sh = Whh_d + (size_t)grow * I_ + c8 * 8;
    const float* si = Wih_d + (size_t)grow * I_ + c8 * 8;
    float4 a = *(const float4*)(sh), b = *(const float4*)(sh + 4);
    float4 c = *(const float4*)(si), d = *(const float4*)(si + 4);
    bf16x8 oh, oi;
    oh[0]=(__bf16)a.x; oh[1]=(__bf16)a.y; oh[2]=(__bf16)a.z; oh[3]=(__bf16)a.w;
    oh[4]=(__bf16)b.x; oh[5]=(__bf16)b.y; oh[6]=(__bf16)b.z; oh[7]=(__bf16)b.w;
    oi[0]=(__bf16)c.x; oi[1]=(__bf16)c.y; oi[2]=(__bf16)c.z; oi[3]=(__bf16)c.w;
    oi[4]=(__bf16)d.x; oi[5]=(__bf16)d.y; oi[6]=(__bf16)d.z; oi[7]=(__bf16)d.w;
    *(bf16x8*)(Ahh + dst) = oh;
    *(bf16x8*)(Aih + dst) = oi;
  }
  __syncthreads();

  int wave = threadIdx.x >> 6, lane = threadIdx.x & 63;
  int col = lane & 15, hi = lane >> 4;
  int b = m0 + wave * 16 + col;          // this thread's batch (B-frag row & D col)
  int j = j0 + hi * 4;                   // this thread's j base (D rows hi*4+r)
  const float* bhh = dir ? bhh_b : bhh_f;
  const float* bih = dir ? bih_b : bih_f;
  float4 bhr = *(const float4*)(bhh + j);
  float4 bhz = *(const float4*)(bhh + H_ + j);
  float4 bhn = *(const float4*)(bhh + 2 * H_ + j);
  float4 bxr = *(const float4*)(bih + j);
  float4 bxz = *(const float4*)(bih + H_ + j);
  float4 bxn = *(const float4*)(bih + 2 * H_ + j);
  float bhhA[3][4] = {{bhr.x,bhr.y,bhr.z,bhr.w},{bhz.x,bhz.y,bhz.z,bhz.w},{bhn.x,bhn.y,bhn.z,bhn.w}};
  float bihA[3][4] = {{bxr.x,bxr.y,bxr.z,bxr.w},{bxz.x,bxz.y,bxz.z,bxz.w},{bxn.x,bxn.y,bxn.z,bxn.w}};
  int rb0 = (0 * 16 + col) * 512, rb1 = (1 * 16 + col) * 512, rb2 = (2 * 16 + col) * 512;
  int csw = col & 7;
  const __bf16* embB = emb + (size_t)b * S_ * I_;   // this thread's batch row base

  const size_t STEPBUF = (size_t)2 * B_ * (H_ / 4);   // u64s per step buffer
  size_t hoff = ((size_t)dir * B_ + b) * (H_ / 4);    // this thread's row in a step buf

  float hprev[4] = {0.f, 0.f, 0.f, 0.f};  // fp32 carry, register-resident

  for (int step = 0; step < S_; ++step) {
    int t = dir ? (S_ - 1 - step) : step;
    const __bf16* erow = embB + (size_t)t * I_;

    // emb loads + xp phase are flag-independent: run them BEFORE the poll so
    // the producers' latency is covered by useful work.
    bf16x8 eb[16];
    #pragma unroll
    for (int kk = 0; kk < 16; ++kk)
      eb[kk] = *(const bf16x8*)(erow + kk * 32 + hi * 8);

    f32x4 ax0 = {0,0,0,0}, ax1 = {0,0,0,0}, ax2 = {0,0,0,0};
    #pragma unroll
    for (int kk = 0; kk < 16; ++kk) {
      int go = ((kk * 4 + hi) ^ csw) * 8;
      bf16x8 w0 = *(const bf16x8*)(Aih + rb0 + go);
      bf16x8 w1 = *(const bf16x8*)(Aih + rb1 + go);
      bf16x8 w2 = *(const bf16x8*)(Aih + rb2 + go);
      ax0 = __builtin_amdgcn_mfma_f32_16x16x32_bf16(w0, eb[kk], ax0, 0, 0, 0);
      ax1 = __builtin_amdgcn_mfma_f32_16x16x32_bf16(w1, eb[kk], ax1, 0, 0, 0);
      ax2 = __builtin_amdgcn_mfma_f32_16x16x32_bf16(w2, eb[kk], ax2, 0, 0, 0);
    }

    if (step != 0) {
      // acquire: wait for all 32 producer blocks x 4 waves of buf[step]
      // (run-ahead allowed — buffers are never reused)
      if (threadIdx.x < 128) {
        const unsigned* pf = bar + (((unsigned)step * 4 + grp) * 128 + threadIdx.x) * 4;
        while (__hip_atomic_load(pf, __ATOMIC_RELAXED, __HIP_MEMORY_SCOPE_AGENT) == 0u) {}
      }
      __syncthreads();
    }

    const u64* hin = hbf + (size_t)step * STEPBUF + hoff;
    u64 hb[32];
    #pragma unroll
    for (int kk = 0; kk < 16; ++kk) {
      hb[2 * kk]     = __hip_atomic_load(hin + kk * 8 + hi * 2, __ATOMIC_RELAXED,
                                         __HIP_MEMORY_SCOPE_AGENT);
      hb[2 * kk + 1] = __hip_atomic_load(hin + kk * 8 + hi * 2 + 1, __ATOMIC_RELAXED,
                                         __HIP_MEMORY_SCOPE_AGENT);
    }

    f32x4 ah0 = {0,0,0,0}, ah1 = {0,0,0,0}, ah2 = {0,0,0,0};
    #pragma unroll
    for (int kk = 0; kk < 16; ++kk) {
      union { u64 u[2]; bf16x8 v; } bu;
      bu.u[0] = hb[2 * kk];
      bu.u[1] = hb[2 * kk + 1];
      int go = ((kk * 4 + hi) ^ csw) * 8;
      bf16x8 a0 = *(const bf16x8*)(Ahh + rb0 + go);
      bf16x8 a1 = *(const bf16x8*)(Ahh + rb1 + go);
      bf16x8 a2 = *(const bf16x8*)(Ahh + rb2 + go);
      ah0 = __builtin_amdgcn_mfma_f32_16x16x32_bf16(a0, bu.v, ah0, 0, 0, 0);
      ah1 = __builtin_amdgcn_mfma_f32_16x16x32_bf16(a1, bu.v, ah1, 0, 0, 0);
      ah2 = __builtin_amdgcn_mfma_f32_16x16x32_bf16(a2, bu.v, ah2, 0, 0, 0);
    }

    union { u64 u; __bf16 h[4]; } pk;
    #pragma unroll
    for (int r = 0; r < 4; r++) {
      float hr = ah0[r] + bhhA[0][r];
      float hz = ah1[r] + bhhA[1][r];
      float hn = ah2[r] + bhhA[2][r];
      float xr = ax0[r] + bihA[0][r];
      float xz = ax1[r] + bihA[1][r];
      float xn = ax2[r] + bihA[2][r];
      float rg = 1.f / (1.f + __expf(-(xr + hr)));
      float zg = 1.f / (1.f + __expf(-(xz + hz)));
      float ng = tanhf(xn + rg * hn);
      float hnew = (1.f - zg) * ng + zg * hprev[r];
      hprev[r] = hnew;                    // fp32 carry stays in registers
      pk.h[r] = (__bf16)hnew;
    }

    if (step != S_ - 1) {
      // bf16 copy for peers' next-step matvec: write-once buf[step+1].
      // Per-wave release: this wave's sc1 store -> vmcnt(0) ack -> wave flag.
      u64* hout = hbf + (size_t)(step + 1) * STEPBUF + hoff;
      __hip_atomic_store(hout + (j0 >> 2) + hi, pk.u, __ATOMIC_RELAXED,
                         __HIP_MEMORY_SCOPE_AGENT);
      asm volatile("s_waitcnt vmcnt(0)" ::: "memory");
      if (lane == 0)
        __hip_atomic_store(bar + (((unsigned)(step + 1) * 4 + grp) * 128 +
                                  myi * 4 + wave) * 4,
                           1u, __ATOMIC_RELAXED, __HIP_MEMORY_SCOPE_AGENT);
    }

    // hs (consumed by k_attn after a dispatch boundary) stored AFTER the
    // release — its ack is drained by the NEXT step's vmcnt(0), off-chain.
    float4 hv = {hprev[0], hprev[1], hprev[2], hprev[3]};
    *(float4*)(hs + ((size_t)b * S_ + t) * (2 * H_) + dir * H_ + j) = hv;
  }
}

// ---------------- K4: beta attention + final linear + softmax ----------------
__global__ __launch_bounds__(256) void k_attn(
    const float* __restrict__ hs, const float* __restrict__ c2w,
    const float* __restrict__ c2b, const float* __restrict__ lin_w,
    const float* __restrict__ lin_b, float* __restrict__ out,
    float* __restrict__ beta_out)
{
  int b = blockIdx.x, tid = threadIdx.x;
  const float* st = hs + (size_t)b * S_ * (2 * H_);
  __shared__ float lg[NF_][S_];
  __shared__ float betas[NF_][S_];
  __shared__ float ctx[NF_ * 2 * H_];
  __shared__ float red[2][4];

  if (tid < NF_ * S_) {
    int f = tid / S_, s = tid - f * S_;
    const float4* sv = (const float4*)(st + (size_t)s * (2 * H_));
    const float4* wv = (const float4*)(c2w + (size_t)f * (2 * H_));
    float a = 0.f;
    for (int k = 0; k < 256; k++) {
      float4 x = sv[k], y = wv[k];
      a += x.x * y.x + x.y * y.y + x.z * y.z + x.w * y.w;
    }
    lg[f][s] = a + c2b[f];
  }
  __syncthreads();

  int wv_ = tid >> 6, ln = tid & 63;
  {
    float v = (ln < S_) ? lg[wv_][ln] : -3.4e38f;
    float m = v;
    #pragma unroll
    for (int off = 32; off >= 1; off >>= 1) m = fmaxf(m, __shfl_xor(m, off));
    float e = (ln < S_) ? __expf(v - m) : 0.f;
    float ssum = e;
    #pragma unroll
    for (int off = 32; off >= 1; off >>= 1) ssum += __shfl_xor(ssum, off);
    if (ln < S_) {
      float bta = e / ssum;
      betas[wv_][ln] = bta;
      beta_out[((size_t)b * NF_ + wv_) * S_ + ln] = bta;
    }
  }
  __syncthreads();

  for (int idx = tid; idx < NF_ * 2 * H_; idx += 256) {
    int f = idx >> 10, h = idx & 1023;
    float a = 0.f;
    for (int s = 0; s < S_; s++) a += betas[f][s] * st[(size_t)s * (2 * H_) + h];
    ctx[idx] = a;
  }
  __syncthreads();

  float p0 = 0.f, p1 = 0.f;
  for (int idx = tid; idx < NF_ * 2 * H_; idx += 256) {
    float c = ctx[idx];
    p0 += c * lin_w[idx];
    p1 += c * lin_w[NF_ * 2 * H_ + idx];
  }
  #pragma unroll
  for (int off = 32; off >= 1; off >>= 1) {
    p0 += __shfl_xor(p0, off);
    p1 += __shfl_xor(p1, off);
  }
  if (ln == 0) { red[0][wv_] = p0; red[1][wv_] = p1; }
  __syncthreads();
  if (tid == 0) {
    float l0 = red[0][0] + red[0][1] + red[0][2] + red[0][3] + lin_b[0];
    float l1 = red[1][0] + red[1][1] + red[1][2] + red[1][3] + lin_b[1];
    float m = fmaxf(l0, l1);
    float e0 = __expf(l0 - m), e1 = __expf(l1 - m);
    float s = e0 + e1;
    out[(size_t)b * O_ + 0] = e0 / s;
    out[(size_t)b * O_ + 1] = e1 / s;
  }
}

// ---------------- launch ----------------
extern "C" void kernel_launch(void* const* d_in, const int* in_sizes, int n_in,
                              void* d_out, int out_size, void* d_ws, size_t ws_size,
                              hipStream_t stream) {
  const float* inputs = (const float*)d_in[0];
  const float* conv_w = (const float*)d_in[1];
  const float* conv_b = (const float*)d_in[2];
  const float* wih_f  = (const float*)d_in[3];
  const float* whh_f  = (const float*)d_in[4];
  const float* bih_f  = (const float*)d_in[5];
  const float* bhh_f  = (const float*)d_in[6];
  const float* wih_b  = (const float*)d_in[7];
  const float* whh_b  = (const float*)d_in[8];
  const float* bih_b  = (const float*)d_in[9];
  const float* bhh_b  = (const float*)d_in[10];
  const float* c2w    = (const float*)d_in[11];
  const float* c2b    = (const float*)d_in[12];
  const float* lin_w  = (const float*)d_in[13];
  const float* lin_b  = (const float*)d_in[14];

  float* out   = (float*)d_out;
  float* alpha = out + B_ * O_;                       // [B,S,P]
  float* beta  = alpha + (size_t)B_ * S_ * P_;        // [B,NF,S]

  char* ws = (char*)d_ws;
  __bf16* emb_bf = (__bf16*)ws;                       // 6,291,456 B  [B][S][I]
  float*  hs     = (float*)(ws + 6291456);            // 25,165,824 B [B][S][2H]
  unsigned* bar  = (unsigned*)(ws + 31457280);        // 393,216 B    [S][4][32][4]x16B flags
  u64*    hbf    = (u64*)(ws + 31858688);             // 12,845,056 B [S+1][2][B][H/4]

  // zero flags + step-0 h buffer (contiguous: bar then hbf[0])
  hipMemsetAsync((void*)bar, 0, 401408 + 262144, stream);
  k_alpha_emb<<<B_ * S_, 960, 0, stream>>>(inputs, conv_w, conv_b, alpha, emb_bf);

  {
    const __bf16* emb_arg = emb_bf;
    void* args[] = {(void*)&whh_f, (void*)&whh_b, (void*)&wih_f, (void*)&wih_b,
                    (void*)&bhh_f, (void*)&bhh_b, (void*)&bih_f, (void*)&bih_b,
                    (void*)&emb_arg, (void*)&hbf, (void*)&hs, (void*)&bar};
    hipLaunchCooperativeKernel((void*)k_gru_all, dim3(128), dim3(256), args, 0, stream);
  }

  k_attn<<<B_, 256, 0, stream>>>(hs, c2w, c2b, lin_w, lin_b, out, beta);
}

// Round 5
// 578.288 us; speedup vs baseline: 1.0447x; 1.0447x over previous
//
#include <hip/hip_runtime.h>

#define B_ 128
#define S_ 48
#define P_ 60
#define I_ 512
#define H_ 512
#define G3 1536   // 3*H
#define NF_ 4
#define O_ 2

typedef __bf16 bf16x8 __attribute__((ext_vector_type(8)));
typedef float f32x4 __attribute__((ext_vector_type(4)));
typedef unsigned long long u64;

// ---------------- K1: fused alpha + emb (single pass over 755MB inputs) ----------------
__global__ __launch_bounds__(960) void k_alpha_emb(
    const float* __restrict__ x, const float* __restrict__ cw,
    const float* __restrict__ cb, float* __restrict__ alpha_out,
    __bf16* __restrict__ emb_bf)
{
  int bs   = blockIdx.x;
  int tid  = threadIdx.x;
  int wave = tid >> 6, lane = tid & 63;
  const float* xb = x + (size_t)bs * (P_ * I_);

  float w[8];
  {
    const float4* c4 = (const float4*)(cw + lane * 8);
    float4 a = c4[0], b = c4[1];
    w[0]=a.x; w[1]=a.y; w[2]=a.z; w[3]=a.w; w[4]=b.x; w[5]=b.y; w[6]=b.z; w[7]=b.w;
  }
  float cb0 = cb[0];
  float acc[8] = {0,0,0,0,0,0,0,0};
  __shared__ float part[15][512];

  for (int p = wave; p < P_; p += 15) {
    const float4* xr = (const float4*)(xb + (size_t)p * I_ + lane * 8);
    float4 a = xr[0], b = xr[1];
    float xv[8] = {a.x,a.y,a.z,a.w,b.x,b.y,b.z,b.w};
    float d = 0.f;
    #pragma unroll
    for (int j = 0; j < 8; j++) d += xv[j] * w[j];
    #pragma unroll
    for (int off = 32; off >= 1; off >>= 1) d += __shfl_xor(d, off);
    float al = fminf(fmaxf(d + cb0, 0.f), 1.f);
    if (lane == 0) alpha_out[(size_t)bs * P_ + p] = al;
    #pragma unroll
    for (int j = 0; j < 8; j++) acc[j] += al * xv[j];
  }
  #pragma unroll
  for (int j = 0; j < 8; j++) part[wave][lane * 8 + j] = acc[j];
  __syncthreads();
  if (tid < 512) {
    float s = 0.f;
    #pragma unroll
    for (int wv = 0; wv < 15; wv++) s += part[wv][tid];
    emb_bf[(size_t)bs * I_ + tid] = (__bf16)s;   // layout [b][s][k]
  }
}

// ---------------- K3: ALL 48 GRU steps, persistent, x-projection FUSED ----------------
// R20: RE-ANCHOR. This is the R15 kernel (572us proven) restored VERBATIM —
// R16's reschedule, R17's xp buffer, R18's register-Whh, R19's data-as-flag
// all failed or regressed and are fully reverted. Single delta vs R15, with a
// correctness precedent in the passing R16: the hs store moves BELOW the
// release (h-store -> __syncthreads -> flag), so the per-step vmcnt(0) drain
// inside __syncthreads waits only on the 8B h-word, not the 16B/thread hs
// store; the hs ack retires during the next step's poll/load phase.
// Protocol (R9-proven release, R15 flag layout) untouched: per-step write-once
// h buffers, run-ahead allowed; poll by threads<32 on 64B-stride flags;
// sc1 agent-scope h stores; flags set only after the syncthreads drain.
__global__ __launch_bounds__(256) void k_gru_all(
    const float* __restrict__ whh_f, const float* __restrict__ whh_b,
    const float* __restrict__ wih_f, const float* __restrict__ wih_b,
    const float* __restrict__ bhh_f, const float* __restrict__ bhh_b,
    const float* __restrict__ bih_f, const float* __restrict__ bih_b,
    const __bf16* __restrict__ emb,      // [B][S][I] bf16
    u64* __restrict__ hbf,               // [S+1][2 dir][B][H/4] bf16x4-as-u64
    float* __restrict__ hs,              // [B][S][2H] fp32
    unsigned* __restrict__ bar)          // [S][4 grp][32 blk] x 16-u32 stride
{
  int bid = blockIdx.x;
  int dir = bid >> 6;                    // 64 blocks per dir
  int j0  = (bid & 31) * 16;             // j-chunk of 16
  int m0  = ((bid >> 5) & 1) * 64;       // batch-half of 64
  int myi = bid & 31;                    // index within sync group
  int grp = bid >> 5;                    // group = (dir, batch-half), 0..3
  const float* Whh_d = dir ? whh_b : whh_f;    // fp32 [3H][I]
  const float* Wih_d = dir ? wih_b : wih_f;

  // weight slices in LDS: rows = 3 gates x 16 j, 512 k; 16B-granule XOR swizzle.
  __shared__ __bf16 Ahh[48 * 512];
  __shared__ __bf16 Aih[48 * 512];
  for (int it = threadIdx.x; it < 48 * 64; it += 256) {
    int r = it >> 6, c8 = it & 63;
    int grow = (r >> 4) * H_ + j0 + (r & 15);
    int dst = r * 512 + ((c8 ^ (r & 7)) * 8);
    const float* sh = Whh_d + (size_t)grow * I_ + c8 * 8;
    const float* si = Wih_d + (size_t)grow * I_ + c8 * 8;
    float4 a = *(const float4*)(sh), b = *(const float4*)(sh + 4);
    float4 c = *(const float4*)(si), d = *(const float4*)(si + 4);
    bf16x8 oh, oi;
    oh[0]=(__bf16)a.x; oh[1]=(__bf16)a.y; oh[2]=(__bf16)a.z; oh[3]=(__bf16)a.w;
    oh[4]=(__bf16)b.x; oh[5]=(__bf16)b.y; oh[6]=(__bf16)b.z; oh[7]=(__bf16)b.w;
    oi[0]=(__bf16)c.x; oi[1]=(__bf16)c.y; oi[2]=(__bf16)c.z; oi[3]=(__bf16)c.w;
    oi[4]=(__bf16)d.x; oi[5]=(__bf16)d.y; oi[6]=(__bf16)d.z; oi[7]=(__bf16)d.w;
    *(bf16x8*)(Ahh + dst) = oh;
    *(bf16x8*)(Aih + dst) = oi;
  }
  __syncthreads();

  int wave = threadIdx.x >> 6, lane = threadIdx.x & 63;
  int col = lane & 15, hi = lane >> 4;
  int b = m0 + wave * 16 + col;          // this thread's batch (B-frag row & D col)
  int j = j0 + hi * 4;                   // this thread's j base (D rows hi*4+r)
  const float* bhh = dir ? bhh_b : bhh_f;
  const float* bih = dir ? bih_b : bih_f;
  float4 bhr = *(const float4*)(bhh + j);
  float4 bhz = *(const float4*)(bhh + H_ + j);
  float4 bhn = *(const float4*)(bhh + 2 * H_ + j);
  float4 bxr = *(const float4*)(bih + j);
  float4 bxz = *(const float4*)(bih + H_ + j);
  float4 bxn = *(const float4*)(bih + 2 * H_ + j);
  float bhhA[3][4] = {{bhr.x,bhr.y,bhr.z,bhr.w},{bhz.x,bhz.y,bhz.z,bhz.w},{bhn.x,bhn.y,bhn.z,bhn.w}};
  float bihA[3][4] = {{bxr.x,bxr.y,bxr.z,bxr.w},{bxz.x,bxz.y,bxz.z,bxz.w},{bxn.x,bxn.y,bxn.z,bxn.w}};
  int rb0 = (0 * 16 + col) * 512, rb1 = (1 * 16 + col) * 512, rb2 = (2 * 16 + col) * 512;
  int csw = col & 7;
  const __bf16* embB = emb + (size_t)b * S_ * I_;   // this thread's batch row base

  const size_t STEPBUF = (size_t)2 * B_ * (H_ / 4);   // u64s per step buffer
  size_t hoff = ((size_t)dir * B_ + b) * (H_ / 4);    // this thread's row in a step buf

  float hprev[4] = {0.f, 0.f, 0.f, 0.f};  // fp32 carry, register-resident

  for (int step = 0; step < S_; ++step) {
    int t = dir ? (S_ - 1 - step) : step;
    const __bf16* erow = embB + (size_t)t * I_;

    // emb loads are flag-independent: issue them BEFORE the poll so their
    // latency overlaps the wait.
    bf16x8 eb[16];
    #pragma unroll
    for (int kk = 0; kk < 16; ++kk)
      eb[kk] = *(const bf16x8*)(erow + kk * 32 + hi * 8);

    if (step != 0) {
      // acquire: wait for all 32 producers of buf[step] (run-ahead allowed —
      // no upper barrier; buffers are never reused)
      if (threadIdx.x < 32) {
        const unsigned* pf = bar + (((unsigned)step * 4 + grp) * 32 + threadIdx.x) * 16;
        while (__hip_atomic_load(pf, __ATOMIC_RELAXED, __HIP_MEMORY_SCOPE_AGENT) == 0u) {}
      }
      __syncthreads();
    }

    const u64* hin = hbf + (size_t)step * STEPBUF + hoff;
    u64 hb[32];
    #pragma unroll
    for (int kk = 0; kk < 16; ++kk) {
      hb[2 * kk]     = __hip_atomic_load(hin + kk * 8 + hi * 2, __ATOMIC_RELAXED,
                                         __HIP_MEMORY_SCOPE_AGENT);
      hb[2 * kk + 1] = __hip_atomic_load(hin + kk * 8 + hi * 2 + 1, __ATOMIC_RELAXED,
                                         __HIP_MEMORY_SCOPE_AGENT);
    }

    f32x4 ah0 = {0,0,0,0}, ah1 = {0,0,0,0}, ah2 = {0,0,0,0};
    f32x4 ax0 = {0,0,0,0}, ax1 = {0,0,0,0}, ax2 = {0,0,0,0};
    #pragma unroll
    for (int kk = 0; kk < 16; ++kk) {
      union { u64 u[2]; bf16x8 v; } bu;
      bu.u[0] = hb[2 * kk];
      bu.u[1] = hb[2 * kk + 1];
      int go = ((kk * 4 + hi) ^ csw) * 8;
      bf16x8 a0 = *(const bf16x8*)(Ahh + rb0 + go);
      bf16x8 a1 = *(const bf16x8*)(Ahh + rb1 + go);
      bf16x8 a2 = *(const bf16x8*)(Ahh + rb2 + go);
      bf16x8 w0 = *(const bf16x8*)(Aih + rb0 + go);
      bf16x8 w1 = *(const bf16x8*)(Aih + rb1 + go);
      bf16x8 w2 = *(const bf16x8*)(Aih + rb2 + go);
      ah0 = __builtin_amdgcn_mfma_f32_16x16x32_bf16(a0, bu.v, ah0, 0, 0, 0);
      ax0 = __builtin_amdgcn_mfma_f32_16x16x32_bf16(w0, eb[kk], ax0, 0, 0, 0);
      ah1 = __builtin_amdgcn_mfma_f32_16x16x32_bf16(a1, bu.v, ah1, 0, 0, 0);
      ax1 = __builtin_amdgcn_mfma_f32_16x16x32_bf16(w1, eb[kk], ax1, 0, 0, 0);
      ah2 = __builtin_amdgcn_mfma_f32_16x16x32_bf16(a2, bu.v, ah2, 0, 0, 0);
      ax2 = __builtin_amdgcn_mfma_f32_16x16x32_bf16(w2, eb[kk], ax2, 0, 0, 0);
    }

    union { u64 u; __bf16 h[4]; } pk;
    #pragma unroll
    for (int r = 0; r < 4; r++) {
      float hr = ah0[r] + bhhA[0][r];
      float hz = ah1[r] + bhhA[1][r];
      float hn = ah2[r] + bhhA[2][r];
      float xr = ax0[r] + bihA[0][r];
      float xz = ax1[r] + bihA[1][r];
      float xn = ax2[r] + bihA[2][r];
      float rg = 1.f / (1.f + __expf(-(xr + hr)));
      float zg = 1.f / (1.f + __expf(-(xz + hz)));
      float ng = tanhf(xn + rg * hn);
      float hnew = (1.f - zg) * ng + zg * hprev[r];
      hprev[r] = hnew;                    // fp32 carry stays in registers
      pk.h[r] = (__bf16)hnew;
    }

    if (step != S_ - 1) {
      // bf16 copy for peers' next-step matvec: write-once buf[step+1]
      u64* hout = hbf + (size_t)(step + 1) * STEPBUF + hoff;
      __hip_atomic_store(hout + (j0 >> 2) + hi, pk.u, __ATOMIC_RELAXED,
                         __HIP_MEMORY_SCOPE_AGENT);
      // release: __syncthreads emits s_waitcnt vmcnt(0) before s_barrier ->
      // every wave's sc1 h-store is acked at the coherence point first.
      __syncthreads();
      if (threadIdx.x == 0)
        __hip_atomic_store(bar + (((unsigned)(step + 1) * 4 + grp) * 32 + myi) * 16,
                           1u, __ATOMIC_RELAXED, __HIP_MEMORY_SCOPE_AGENT);
    }

    // hs (consumed by k_attn after a dispatch boundary) stored AFTER the
    // release: the per-step vmcnt(0) drain no longer waits on this 16B/thread
    // store; it retires during the next step's poll/load phase. (This ordering
    // was part of the passing R16.)
    float4 hv = {hprev[0], hprev[1], hprev[2], hprev[3]};
    *(float4*)(hs + ((size_t)b * S_ + t) * (2 * H_) + dir * H_ + j) = hv;
  }
}

// ---------------- K4: beta attention + final linear + softmax ----------------
__global__ __launch_bounds__(256) void k_attn(
    const float* __restrict__ hs, const float* __restrict__ c2w,
    const float* __restrict__ c2b, const float* __restrict__ lin_w,
    const float* __restrict__ lin_b, float* __restrict__ out,
    float* __restrict__ beta_out)
{
  int b = blockIdx.x, tid = threadIdx.x;
  const float* st = hs + (size_t)b * S_ * (2 * H_);
  __shared__ float lg[NF_][S_];
  __shared__ float betas[NF_][S_];
  __shared__ float ctx[NF_ * 2 * H_];
  __shared__ float red[2][4];

  if (tid < NF_ * S_) {
    int f = tid / S_, s = tid - f * S_;
    const float4* sv = (const float4*)(st + (size_t)s * (2 * H_));
    const float4* wv = (const float4*)(c2w + (size_t)f * (2 * H_));
    float a = 0.f;
    for (int k = 0; k < 256; k++) {
      float4 x = sv[k], y = wv[k];
      a += x.x * y.x + x.y * y.y + x.z * y.z + x.w * y.w;
    }
    lg[f][s] = a + c2b[f];
  }
  __syncthreads();

  int wv_ = tid >> 6, ln = tid & 63;
  {
    float v = (ln < S_) ? lg[wv_][ln] : -3.4e38f;
    float m = v;
    #pragma unroll
    for (int off = 32; off >= 1; off >>= 1) m = fmaxf(m, __shfl_xor(m, off));
    float e = (ln < S_) ? __expf(v - m) : 0.f;
    float ssum = e;
    #pragma unroll
    for (int off = 32; off >= 1; off >>= 1) ssum += __shfl_xor(ssum, off);
    if (ln < S_) {
      float bta = e / ssum;
      betas[wv_][ln] = bta;
      beta_out[((size_t)b * NF_ + wv_) * S_ + ln] = bta;
    }
  }
  __syncthreads();

  for (int idx = tid; idx < NF_ * 2 * H_; idx += 256) {
    int f = idx >> 10, h = idx & 1023;
    float a = 0.f;
    for (int s = 0; s < S_; s++) a += betas[f][s] * st[(size_t)s * (2 * H_) + h];
    ctx[idx] = a;
  }
  __syncthreads();

  float p0 = 0.f, p1 = 0.f;
  for (int idx = tid; idx < NF_ * 2 * H_; idx += 256) {
    float c = ctx[idx];
    p0 += c * lin_w[idx];
    p1 += c * lin_w[NF_ * 2 * H_ + idx];
  }
  #pragma unroll
  for (int off = 32; off >= 1; off >>= 1) {
    p0 += __shfl_xor(p0, off);
    p1 += __shfl_xor(p1, off);
  }
  if (ln == 0) { red[0][wv_] = p0; red[1][wv_] = p1; }
  __syncthreads();
  if (tid == 0) {
    float l0 = red[0][0] + red[0][1] + red[0][2] + red[0][3] + lin_b[0];
    float l1 = red[1][0] + red[1][1] + red[1][2] + red[1][3] + lin_b[1];
    float m = fmaxf(l0, l1);
    float e0 = __expf(l0 - m), e1 = __expf(l1 - m);
    float s = e0 + e1;
    out[(size_t)b * O_ + 0] = e0 / s;
    out[(size_t)b * O_ + 1] = e1 / s;
  }
}

// ---------------- launch ----------------
extern "C" void kernel_launch(void* const* d_in, const int* in_sizes, int n_in,
                              void* d_out, int out_size, void* d_ws, size_t ws_size,
                              hipStream_t stream) {
  const float* inputs = (const float*)d_in[0];
  const float* conv_w = (const float*)d_in[1];
  const float* conv_b = (const float*)d_in[2];
  const float* wih_f  = (const float*)d_in[3];
  const float* whh_f  = (const float*)d_in[4];
  const float* bih_f  = (const float*)d_in[5];
  const float* bhh_f  = (const float*)d_in[6];
  const float* wih_b  = (const float*)d_in[7];
  const float* whh_b  = (const float*)d_in[8];
  const float* bih_b  = (const float*)d_in[9];
  const float* bhh_b  = (const float*)d_in[10];
  const float* c2w    = (const float*)d_in[11];
  const float* c2b    = (const float*)d_in[12];
  const float* lin_w  = (const float*)d_in[13];
  const float* lin_b  = (const float*)d_in[14];

  float* out   = (float*)d_out;
  float* alpha = out + B_ * O_;                       // [B,S,P]
  float* beta  = alpha + (size_t)B_ * S_ * P_;        // [B,NF,S]

  char* ws = (char*)d_ws;
  __bf16* emb_bf = (__bf16*)ws;                       // 6,291,456 B  [B][S][I]
  float*  hs     = (float*)(ws + 6291456);            // 25,165,824 B [B][S][2H]
  unsigned* bar  = (unsigned*)(ws + 31457280);        // 401,408 B    [S][4][32]x16-u32 flags
  u64*    hbf    = (u64*)(ws + 31858688);             // 12,845,056 B [S+1][2][B][H/4]

  // zero flags + step-0 h buffer (contiguous: bar then hbf[0])
  hipMemsetAsync((void*)bar, 0, 401408 + 262144, stream);
  k_alpha_emb<<<B_ * S_, 960, 0, stream>>>(inputs, conv_w, conv_b, alpha, emb_bf);

  {
    const __bf16* emb_arg = emb_bf;
    void* args[] = {(void*)&whh_f, (void*)&whh_b, (void*)&wih_f, (void*)&wih_b,
                    (void*)&bhh_f, (void*)&bhh_b, (void*)&bih_f, (void*)&bih_b,
                    (void*)&emb_arg, (void*)&hbf, (void*)&hs, (void*)&bar};
    hipLaunchCooperativeKernel((void*)k_gru_all, dim3(128), dim3(256), args, 0, stream);
  }

  k_attn<<<B_, 256, 0, stream>>>(hs, c2w, c2b, lin_w, lin_b, out, beta);
}